// Round 1
// baseline (237.829 us; speedup 1.0000x reference)
//
#include <hip/hip_runtime.h>
#include <math.h>

// Problem constants (B=4, S=2048, H=1024, E=16, TOP_K=4)
constexpr int kTokens    = 8192;   // B*S
constexpr int kH         = 1024;
constexpr int kE         = 16;
constexpr int kTopK      = 4;
constexpr int kTokPerBlk = 16;
constexpr int kNBlk      = kTokens / kTokPerBlk;  // 512

// ---------------------------------------------------------------------------
// Kernel 1: per-block (16 tokens) fused logits + softmax + top-k + partial
// expert-prob sums.
// Thread layout: t = (tl = token-lane 0..15, s = slice 0..15), slice s =
// (modality m = s&3, h-quarter hq = s>>2, 256 h each). Each thread produces
// partial logits[16] for its (token, modality, h-range); block reduces in LDS.
// fp32 inner accumulate per 64-h chunk, folded to fp64 — keeps our logits
// ~1e-7 from exact so top-k ordering matches the numpy reference.
// ---------------------------------------------------------------------------
__global__ __launch_bounds__(256)
void router_main(const float* __restrict__ x,   const float* __restrict__ img,
                 const float* __restrict__ txt, const float* __restrict__ aud,
                 const float* __restrict__ Wg,  const float* __restrict__ bg,
                 const float* __restrict__ Wi,  const float* __restrict__ bi,
                 const float* __restrict__ Wt,  const float* __restrict__ bt,
                 const float* __restrict__ Wa,  const float* __restrict__ ba,
                 float* __restrict__ out, float* __restrict__ partials)
{
    __shared__ double red[16][16][16];   // [slice][tok][e]  32 KB
    __shared__ double lgs[16][16];       // [tok][e] logits   2 KB
    __shared__ float  pr[16][16];        // [tok][e] probs    1 KB

    const int t    = threadIdx.x;
    const int tl   = t & 15;        // token-lane within block
    const int s    = t >> 4;        // slice
    const int m    = s & 3;         // modality
    const int hq   = s >> 2;        // h-quarter (256 h)
    const int blk  = blockIdx.x;
    const int gtok = blk * kTokPerBlk + tl;

    const float* xsel = (m == 0) ? x  : (m == 1) ? img : (m == 2) ? txt : aud;
    const float* wsel = (m == 0) ? Wg : (m == 1) ? Wi  : (m == 2) ? Wt  : Wa;
    const float* xbase = xsel + (size_t)gtok * kH + hq * 256;
    const float* wbase = wsel + hq * 256 * kE;

    double dacc[kE];
#pragma unroll
    for (int e = 0; e < kE; ++e) dacc[e] = 0.0;

    for (int c = 0; c < 4; ++c) {        // 4 chunks of 64 h
        float facc[kE];
#pragma unroll
        for (int e = 0; e < kE; ++e) facc[e] = 0.f;

#pragma unroll 4
        for (int msi = 0; msi < 16; ++msi) {   // macro-steps of 4 h
            const int h = c * 64 + msi * 4;
            const float4 xv = *(const float4*)(xbase + h);
#pragma unroll
            for (int j = 0; j < 4; ++j) {
                const float xj = ((const float*)&xv)[j];
                const float4* wr = (const float4*)(wbase + (size_t)(h + j) * kE);
                const float4 w0 = wr[0], w1 = wr[1], w2 = wr[2], w3 = wr[3];
                facc[0]  += xj * w0.x;  facc[1]  += xj * w0.y;
                facc[2]  += xj * w0.z;  facc[3]  += xj * w0.w;
                facc[4]  += xj * w1.x;  facc[5]  += xj * w1.y;
                facc[6]  += xj * w1.z;  facc[7]  += xj * w1.w;
                facc[8]  += xj * w2.x;  facc[9]  += xj * w2.y;
                facc[10] += xj * w2.z;  facc[11] += xj * w2.w;
                facc[12] += xj * w3.x;  facc[13] += xj * w3.y;
                facc[14] += xj * w3.z;  facc[15] += xj * w3.w;
            }
        }
#pragma unroll
        for (int e = 0; e < kE; ++e) dacc[e] += (double)facc[e];
    }

#pragma unroll
    for (int e = 0; e < kE; ++e) red[s][tl][e] = dacc[e];
    __syncthreads();

    // Reduce the 16 slices: thread t -> (tok = t>>4, e = t&15)
    {
        const int tok = t >> 4;
        const int e   = t & 15;
        double sum = 0.0;
#pragma unroll
        for (int ss = 0; ss < 16; ++ss) sum += red[ss][tok][e];
        sum += (double)bg[e] + (double)bi[e] + (double)bt[e] + (double)ba[e];
        lgs[tok][e] = sum;
    }
    __syncthreads();

    // Softmax + top-k: one thread per token (16 active)
    if (t < kTokPerBlk) {
        const int tok = t;
        double mx = lgs[tok][0];
#pragma unroll
        for (int e = 1; e < kE; ++e) mx = fmax(mx, lgs[tok][e]);

        float p[kE];
        float sum = 0.f;
#pragma unroll
        for (int e = 0; e < kE; ++e) {
            p[e] = expf((float)(lgs[tok][e] - mx));
            sum += p[e];
        }
        const float inv = 1.f / sum;
#pragma unroll
        for (int e = 0; e < kE; ++e) {
            p[e] *= inv;
            pr[tok][e] = p[e];
        }

        // top-4, descending, ties -> smallest index (matches jax.lax.top_k)
        unsigned used = 0;
        float tp[kTopK];
        int   ti[kTopK];
        float s4 = 0.f;
#pragma unroll
        for (int k = 0; k < kTopK; ++k) {
            float best = -1.f;
            int   bidx = 0;
#pragma unroll
            for (int e = 0; e < kE; ++e) {
                if (!((used >> e) & 1u) && p[e] > best) { best = p[e]; bidx = e; }
            }
            used |= 1u << bidx;
            tp[k] = best;
            ti[k] = bidx;
            s4 += best;
        }
        const float rn = 1.f / s4;
        const int g = blk * kTokPerBlk + tok;
#pragma unroll
        for (int k = 0; k < kTopK; ++k) {
            out[(size_t)g * kTopK + k] = (float)ti[k];                       // indices as float values
            out[(size_t)kTokens * kTopK + (size_t)g * kTopK + k] = tp[k] * rn; // renormalized probs
        }
    }
    __syncthreads();

    // Block-partial expert prob sums (deterministic; reduced by kernel 2)
    if (t < kE) {
        const int e = t;
        float sumE = 0.f;
#pragma unroll
        for (int tok = 0; tok < kTokPerBlk; ++tok) sumE += pr[tok][e];
        partials[blk * kE + e] = sumE;
    }
}

// ---------------------------------------------------------------------------
// Kernel 2: reduce block partials -> mean prob per expert -> aux loss scalar
// ---------------------------------------------------------------------------
__global__ __launch_bounds__(64)
void router_aux(const float* __restrict__ partials, float* __restrict__ out)
{
    __shared__ double ps[kE];
    const int t = threadIdx.x;
    if (t < kE) {
        double sum = 0.0;
        for (int b = 0; b < kNBlk; ++b) sum += (double)partials[b * kE + t];
        ps[t] = sum / (double)kTokens;
    }
    __syncthreads();
    if (t == 0) {
        double aux = 0.0;
#pragma unroll
        for (int e = 0; e < kE; ++e) {
            const double p = ps[e];
            aux += p * log(p * (double)kE + 1e-9);
        }
        out[(size_t)kTokens * kTopK * 2] = (float)aux;  // element 65536
    }
}

extern "C" void kernel_launch(void* const* d_in, const int* in_sizes, int n_in,
                              void* d_out, int out_size, void* d_ws, size_t ws_size,
                              hipStream_t stream)
{
    const float* x   = (const float*)d_in[0];
    const float* img = (const float*)d_in[1];
    const float* txt = (const float*)d_in[2];
    const float* aud = (const float*)d_in[3];
    const float* Wg  = (const float*)d_in[4];
    const float* bg  = (const float*)d_in[5];
    const float* Wi  = (const float*)d_in[6];
    const float* bi  = (const float*)d_in[7];
    const float* Wt  = (const float*)d_in[8];
    const float* bt  = (const float*)d_in[9];
    const float* Wa  = (const float*)d_in[10];
    const float* ba  = (const float*)d_in[11];

    float* out      = (float*)d_out;
    float* partials = (float*)d_ws;   // 512*16*4 B = 32 KB scratch

    router_main<<<kNBlk, 256, 0, stream>>>(x, img, txt, aud,
                                           Wg, bg, Wi, bi, Wt, bt, Wa, ba,
                                           out, partials);
    router_aux<<<1, 64, 0, stream>>>(partials, out);
}

// Round 2
// 236.962 us; speedup vs baseline: 1.0037x; 1.0037x over previous
//
#include <hip/hip_runtime.h>
#include <math.h>

// Problem constants (B=4, S=2048, H=1024, E=16, TOP_K=4)
constexpr int kTokens = 8192;   // B*S
constexpr int kH      = 1024;
constexpr int kE      = 16;
constexpr int kTopK   = 4;

// ---------------------------------------------------------------------------
// Kernel 1: partial logits per (modality, 16-token tile).
// Grid = 512 token-tiles x 4 modalities = 2048 blocks x 256 threads
//      = 8192 waves (fills the 8192 wave slots of 256 CUs).
// Per 64-h chunk: stage x[16 tok][64 h] into LDS with fully-coalesced float4
// loads (pipelined through a register across the barrier), then each thread
// (tl = token 0..15, sp = 4-h window 0..15) does 64 FMAs against weight rows
// loaded from L1/L2 (wave-instr = 4 distinct 64B rows, 16-lane broadcast).
// fp32 accumulate over this thread's 64 h (same chunk size as the round-1
// kernel that passed); cross-slice reduction in fp64 via LDS.
// ---------------------------------------------------------------------------
__global__ __launch_bounds__(256)
void router_partial(const float* __restrict__ x,   const float* __restrict__ img,
                    const float* __restrict__ txt, const float* __restrict__ aud,
                    const float* __restrict__ Wg,  const float* __restrict__ Wi,
                    const float* __restrict__ Wt,  const float* __restrict__ Wa,
                    float* __restrict__ partials)
{
    // 16 KB shared: chunk buffer [16 tok][68 floats] (pad 4 keeps 16B align,
    // breaks the 64-float power-of-2 stride -> 2-way conflicts only = free),
    // later reused as red[16 sp][16 tok][16 e].
    __shared__ float smem[4096];

    const int t   = threadIdx.x;
    const int tl  = t & 15;     // token lane (compute role)
    const int sp  = t >> 4;     // 4-h window within chunk (compute role)
    const int bid = blockIdx.x;
    const int m   = bid & 3;    // modality (wave-uniform -> scalar branch)
    const int tt  = bid >> 2;   // token tile

    const float* Xm = (m == 0) ? x  : (m == 1) ? img : (m == 2) ? txt : aud;
    const float* Wm = (m == 0) ? Wg : (m == 1) ? Wi  : (m == 2) ? Wt  : Wa;

    // staging roles: row = t>>4 (token), col = t&15 -> consecutive lanes read
    // consecutive 16B -> 256B contiguous per 16 lanes (coalesced).
    const int srow = t >> 4;
    const int scol = t & 15;
    const float* gsrc = Xm + (size_t)(tt * 16 + srow) * kH + scol * 4;

    float facc[kE];
#pragma unroll
    for (int e = 0; e < kE; ++e) facc[e] = 0.f;

    float4 v = *(const float4*)gsrc;   // prefetch chunk 0

    for (int c = 0; c < 16; ++c) {
        __syncthreads();               // previous chunk's consumers done
        *(float4*)&smem[srow * 68 + scol * 4] = v;
        if (c < 15) v = *(const float4*)(gsrc + (c + 1) * 64);  // prefetch next
        __syncthreads();               // chunk ready

        const float4 xq = *(const float4*)&smem[tl * 68 + sp * 4];
        const float* wb = Wm + (size_t)(c * 64 + sp * 4) * kE;
#pragma unroll
        for (int j = 0; j < 4; ++j) {
            const float xj = (j == 0) ? xq.x : (j == 1) ? xq.y : (j == 2) ? xq.z : xq.w;
            const float4* wr = (const float4*)(wb + j * kE);
            const float4 w0 = wr[0], w1 = wr[1], w2 = wr[2], w3 = wr[3];
            facc[0]  += xj * w0.x;  facc[1]  += xj * w0.y;
            facc[2]  += xj * w0.z;  facc[3]  += xj * w0.w;
            facc[4]  += xj * w1.x;  facc[5]  += xj * w1.y;
            facc[6]  += xj * w1.z;  facc[7]  += xj * w1.w;
            facc[8]  += xj * w2.x;  facc[9]  += xj * w2.y;
            facc[10] += xj * w2.z;  facc[11] += xj * w2.w;
            facc[12] += xj * w3.x;  facc[13] += xj * w3.y;
            facc[14] += xj * w3.z;  facc[15] += xj * w3.w;
        }
    }

    // Reduce 16 sp-slices per (token, e) in fp64; write fp32 partial.
    __syncthreads();
    float* red = smem;   // [sp][tok][e]
#pragma unroll
    for (int q = 0; q < 4; ++q) {
        *(float4*)&red[(sp * 16 + tl) * 16 + q * 4] =
            make_float4(facc[q * 4], facc[q * 4 + 1], facc[q * 4 + 2], facc[q * 4 + 3]);
    }
    __syncthreads();
    {
        const int tok = t >> 4;
        const int e   = t & 15;
        double sum = 0.0;
#pragma unroll
        for (int s2 = 0; s2 < 16; ++s2) sum += (double)red[(s2 * 16 + tok) * 16 + e];
        // coalesced: consecutive t -> consecutive (tok,e) floats
        partials[((size_t)m * kTokens + (size_t)tt * 16 + tok) * kE + e] = (float)sum;
    }
}

// ---------------------------------------------------------------------------
// Kernel 2: per-token combine + softmax + top-k + per-block expert sums.
// 128 blocks x 64 threads (1 wave/block, no LDS, no syncthreads).
// ---------------------------------------------------------------------------
__global__ __launch_bounds__(64)
void router_topk(const float* __restrict__ partials,
                 const float* __restrict__ bg, const float* __restrict__ bi,
                 const float* __restrict__ bt, const float* __restrict__ ba,
                 float* __restrict__ out, float* __restrict__ blocksum)
{
    const int t   = threadIdx.x;          // 0..63
    const int tok = blockIdx.x * 64 + t;

    double lg[kE];
#pragma unroll
    for (int e = 0; e < kE; ++e)
        lg[e] = (double)bg[e] + (double)bi[e] + (double)bt[e] + (double)ba[e];

#pragma unroll
    for (int m = 0; m < 4; ++m) {
        const float* pp = partials + ((size_t)m * kTokens + tok) * kE;
#pragma unroll
        for (int q = 0; q < 4; ++q) {
            const float4 vv = *(const float4*)(pp + q * 4);
            lg[q * 4 + 0] += (double)vv.x;  lg[q * 4 + 1] += (double)vv.y;
            lg[q * 4 + 2] += (double)vv.z;  lg[q * 4 + 3] += (double)vv.w;
        }
    }

    double mx = lg[0];
#pragma unroll
    for (int e = 1; e < kE; ++e) mx = fmax(mx, lg[e]);

    float p[kE];
    float sum = 0.f;
#pragma unroll
    for (int e = 0; e < kE; ++e) {
        p[e] = expf((float)(lg[e] - mx));
        sum += p[e];
    }
    const float inv = 1.f / sum;
#pragma unroll
    for (int e = 0; e < kE; ++e) p[e] *= inv;   // softmax probs

    // top-4, descending, ties -> smallest index (matches jax.lax.top_k)
    unsigned used = 0;
    float tp[kTopK];
    int   ti[kTopK];
    float s4 = 0.f;
#pragma unroll
    for (int k = 0; k < kTopK; ++k) {
        float best = -1.f;
        int   bidx = 0;
#pragma unroll
        for (int e = 0; e < kE; ++e) {
            if (!((used >> e) & 1u) && p[e] > best) { best = p[e]; bidx = e; }
        }
        used |= 1u << bidx;
        tp[k] = best;
        ti[k] = bidx;
        s4 += best;
    }
    const float rn = 1.f / s4;

    // coalesced float4 writes: indices as float values, then renorm probs
    float4 oi = make_float4((float)ti[0], (float)ti[1], (float)ti[2], (float)ti[3]);
    float4 op = make_float4(tp[0] * rn, tp[1] * rn, tp[2] * rn, tp[3] * rn);
    *(float4*)&out[(size_t)tok * kTopK] = oi;
    *(float4*)&out[(size_t)kTokens * kTopK + (size_t)tok * kTopK] = op;

    // per-block (64-token) expert sums via wave shuffle reduce
#pragma unroll
    for (int e = 0; e < kE; ++e) {
        float vv = p[e];
#pragma unroll
        for (int off = 32; off > 0; off >>= 1) vv += __shfl_xor(vv, off, 64);
        if (t == 0) blocksum[blockIdx.x * kE + e] = vv;
    }
}

// ---------------------------------------------------------------------------
// Kernel 3: 128 block-partials -> mean prob per expert -> aux loss scalar
// ---------------------------------------------------------------------------
__global__ __launch_bounds__(64)
void router_aux(const float* __restrict__ blocksum, float* __restrict__ out)
{
    __shared__ double ps[kE];
    const int t = threadIdx.x;
    if (t < kE) {
        double s = 0.0;
        for (int b = 0; b < 128; ++b) s += (double)blocksum[b * kE + t];
        ps[t] = s / (double)kTokens;
    }
    __syncthreads();
    if (t == 0) {
        double aux = 0.0;
#pragma unroll
        for (int e = 0; e < kE; ++e) aux += ps[e] * log(ps[e] * (double)kE + 1e-9);
        out[(size_t)kTokens * kTopK * 2] = (float)aux;  // element 65536
    }
}

extern "C" void kernel_launch(void* const* d_in, const int* in_sizes, int n_in,
                              void* d_out, int out_size, void* d_ws, size_t ws_size,
                              hipStream_t stream)
{
    const float* x   = (const float*)d_in[0];
    const float* img = (const float*)d_in[1];
    const float* txt = (const float*)d_in[2];
    const float* aud = (const float*)d_in[3];
    const float* Wg  = (const float*)d_in[4];
    const float* bg  = (const float*)d_in[5];
    const float* Wi  = (const float*)d_in[6];
    const float* bi  = (const float*)d_in[7];
    const float* Wt  = (const float*)d_in[8];
    const float* bt  = (const float*)d_in[9];
    const float* Wa  = (const float*)d_in[10];
    const float* ba  = (const float*)d_in[11];

    float* out      = (float*)d_out;
    float* partials = (float*)d_ws;                        // 4*8192*16*4 = 2 MB
    float* blocksum = (float*)((char*)d_ws + (size_t)4 * kTokens * kE * 4);  // 8 KB

    router_partial<<<2048, 256, 0, stream>>>(x, img, txt, aud, Wg, Wi, Wt, Wa, partials);
    router_topk<<<128, 64, 0, stream>>>(partials, bg, bi, bt, ba, out, blocksum);
    router_aux<<<1, 64, 0, stream>>>(blocksum, out);
}